// Round 9
// baseline (1055.544 us; speedup 1.0000x reference)
//
#include <hip/hip_runtime.h>
#include <hip/hip_bf16.h>

#define NN 768
#define CSD 384
#define CZD 128
#define HD 12
#define DOUT 2112
#define II 2
#define ALS 772                      /* padded a_l row stride (floats) */
#define WBS 132                      /* padded wbT row stride (floats) */

#define SCALE_SINGLE 0.25f
#define SCALE_FRAME (-0.11785113019775793f)   /* -1/sqrt(72) */

__device__ __forceinline__ float dot4f(float4 a, float4 b){
    return fmaf(a.x,b.x, fmaf(a.y,b.y, fmaf(a.z,b.z, a.w*b.w)));
}

// ---------------- K1: projections + frame apply, II=2 residues per block ----------------
__global__ __launch_bounds__(384) void k_proj(
    const float* __restrict__ s, const float* __restrict__ R, const float* __restrict__ tv,
    const float* __restrict__ Wq, const float* __restrict__ Wk, const float* __restrict__ Wv,
    const float* __restrict__ Wqp, const float* __restrict__ Wkp, const float* __restrict__ Wvp,
    float* __restrict__ q, float* __restrict__ k, float* __restrict__ v,
    float* __restrict__ gq, float* __restrict__ gk, float* __restrict__ gv,
    float* __restrict__ sqq, float* __restrict__ sqk)
{
    __shared__ float s_l[II*CSD];
    __shared__ float praw[II][576];
    __shared__ float sq_pt[II][96];
    int i0 = blockIdx.x * II, t = threadIdx.x;
    if (t < II*CSD/4){
        const float4* s4 = (const float4*)(s + (size_t)i0*CSD);
        ((float4*)s_l)[t] = s4[t];
    }
    __syncthreads();

    int cols[3] = {t, t+384, t+768};
    const float* Wp[3]; int st[3], lc[3];
    #pragma unroll
    for (int m=0;m<3;m++){
        int c = cols[m];
        if (c < 192){ Wp[m]=Wq;  st[m]=192; lc[m]=c; }
        else if (c < 384){ Wp[m]=Wk;  st[m]=192; lc[m]=c-192; }
        else if (c < 576){ Wp[m]=Wv;  st[m]=192; lc[m]=c-384; }
        else if (c < 720){ Wp[m]=Wqp; st[m]=144; lc[m]=c-576; }
        else if (c < 864){ Wp[m]=Wkp; st[m]=144; lc[m]=c-720; }
        else { Wp[m]=Wvp; st[m]=288; lc[m]=c-864; }
    }
    float acc[3][II];
    #pragma unroll
    for (int m=0;m<3;m++)
        #pragma unroll
        for (int ii=0;ii<II;ii++) acc[m][ii]=0.f;

    #pragma unroll 4
    for (int r=0;r<CSD;r++){
        float w0 = Wp[0][(size_t)r*st[0]+lc[0]];
        float w1 = Wp[1][(size_t)r*st[1]+lc[1]];
        float w2 = Wp[2][(size_t)r*st[2]+lc[2]];
        #pragma unroll
        for (int ii=0;ii<II;ii++){
            float sv = s_l[ii*CSD + r];
            acc[0][ii] = fmaf(sv, w0, acc[0][ii]);
            acc[1][ii] = fmaf(sv, w1, acc[1][ii]);
            acc[2][ii] = fmaf(sv, w2, acc[2][ii]);
        }
    }
    #pragma unroll
    for (int m=0;m<3;m++){
        int c = cols[m];
        #pragma unroll
        for (int ii=0;ii<II;ii++){
            float val = acc[m][ii];
            size_t i = i0 + ii;
            if (c < 192) q[i*192 + c] = val;
            else if (c < 384) k[i*192 + (c-192)] = val;
            else if (c < 576) v[i*192 + (c-384)] = val;
            else praw[ii][c-576] = val;
        }
    }
    __syncthreads();

    if (t < 192){
        #pragma unroll
        for (int ii=0;ii<II;ii++){
            size_t i = i0 + ii;
            const float* Ri = R + i*9;
            float R00=Ri[0],R01=Ri[1],R02=Ri[2];
            float R10=Ri[3],R11=Ri[4],R12=Ri[5];
            float R20=Ri[6],R21=Ri[7],R22=Ri[8];
            float t0=tv[i*3+0],t1=tv[i*3+1],t2=tv[i*3+2];
            int src; float* dst; int sqslot=-1;
            if (t < 48){ src = t*3; dst = gq + i*144 + t*3; sqslot = t; }
            else if (t < 96){ int u=t-48; src = 144+u*3; dst = gk + i*144 + u*3; sqslot = 48+u; }
            else { int u=t-96; src = 288+u*3; dst = gv + i*288 + u*3; }
            float x=praw[ii][src], y=praw[ii][src+1], zc=praw[ii][src+2];
            float g0 = fmaf(R00,x, fmaf(R01,y, fmaf(R02,zc, t0)));
            float g1 = fmaf(R10,x, fmaf(R11,y, fmaf(R12,zc, t1)));
            float g2 = fmaf(R20,x, fmaf(R21,y, fmaf(R22,zc, t2)));
            dst[0]=g0; dst[1]=g1; dst[2]=g2;
            if (sqslot >= 0) sq_pt[ii][sqslot] = g0*g0 + g1*g1 + g2*g2;
        }
    }
    __syncthreads();
    if (t < II*HD){
        int ii = t / HD, h = t % HD;
        float s1 = sq_pt[ii][h*4]+sq_pt[ii][h*4+1]+sq_pt[ii][h*4+2]+sq_pt[ii][h*4+3];
        float s2 = sq_pt[ii][48+h*4]+sq_pt[ii][48+h*4+1]+sq_pt[ii][48+h*4+2]+sq_pt[ii][48+h*4+3];
        sqq[(size_t)(i0+ii)*HD + h] = s1;
        sqk[(size_t)(i0+ii)*HD + h] = s2;
    }
}

// ---------------- K2: fused IPA, balanced waves + 2 blocks/CU ----------------
// 512 threads = 8 waves, ~76KB LDS -> 2 blocks/CU.
// Phase A (24 tiles x 32 z-rows, 2-buffer __syncthreads pipeline, all threads stage):
//   waves 0-5: pair term. lane=(rlow, c4-half f, head-low hl); Wb half preloaded in
//              16 f4 VGPRs (zero Wb LDS traffic in loop); half-dots combined shfl_xor(16).
//   waves 6-7: single+frame from L2 (reg-preloaded q/gq), RMW into a_l one tile behind.
// Softmax: waves 0-5, 2 heads each. Phase B: waves 0-5 o_z (1 head/lane), 6-7 o_s/so.
__global__ __launch_bounds__(512, 4) void k_ipa(
    const float* __restrict__ z, const float* __restrict__ Wb, const float* __restrict__ scale_head,
    const float* __restrict__ q, const float* __restrict__ k,
    const float* __restrict__ gq, const float* __restrict__ gk,
    const float* __restrict__ sqq, const float* __restrict__ sqk,
    const float* __restrict__ v, const float* __restrict__ gv,
    const float* __restrict__ R, const float* __restrict__ tv,
    float* __restrict__ att)
{
    __shared__ float ztile[2][32][CZD];   // 32KB staging dbuf
    __shared__ float wbT[HD*WBS];         // padded [h][c] (used once for reg preload)
    __shared__ float a_l[HD*ALS];         // padded logits -> attention
    __shared__ float so_l[288];

    int i = blockIdx.x, t = threadIdx.x;
    int wave = t >> 6, lane = t & 63;

    for (int idx=t; idx<HD*CZD; idx+=512){
        int h = idx >> 7, c = idx & 127;
        wbT[h*WBS + c] = Wb[(size_t)c*HD + h];
    }

    const char* zi = (const char*)(z + (size_t)i*NN*CZD);
    float* zbase = &ztile[0][0][0];

    // stage one 32-row (16KB) tile; all 512 threads, 2 x 16B each.
#define STAGEA(JT, BUF) do { \
    const char* _zb = zi + (size_t)(JT)*16384; \
    char* _lb = (char*)zbase + (size_t)(BUF)*16384; \
    _Pragma("unroll") \
    for (int _m=0;_m<2;_m++){ \
        int _d = t*16 + _m*8192; \
        int _j = _d >> 9; \
        int _b = _d & 511; \
        int _sb = _b ^ ((_j & 31) << 4); \
        __builtin_amdgcn_global_load_lds((const __attribute__((address_space(1))) void*)(_zb + (size_t)_j*512 + _sb), \
            (__attribute__((address_space(3))) void*)(_lb + _d), 16, 0, 0); \
    } \
  } while(0)

#define STAGEB(JT, BUF) do { \
    const char* _zb = zi + (size_t)(JT)*16384; \
    char* _lb = (char*)zbase + (size_t)(BUF)*16384; \
    _Pragma("unroll") \
    for (int _m=0;_m<2;_m++){ \
        int _d = t*16 + _m*8192; \
        __builtin_amdgcn_global_load_lds((const __attribute__((address_space(1))) void*)(_zb + _d), \
            (__attribute__((address_space(3))) void*)(_lb + _d), 16, 0, 0); \
    } \
  } while(0)

    // role register state
    int rlow = lane & 15, fh = (lane >> 4) & 1, hl = lane >> 5;
    int hpair = wave*2 + hl;                          // waves 0-5: head 0..11
    int rS = lane & 31, gS = (wave-6)*2 + (lane>>5);  // waves 6-7: head-triples 0..3
    float4 qv[3][4]; float4 gqv[3][3]; float sqq3[3], sp3[3];
    if (wave >= 6){
        #pragma unroll
        for (int hs=0; hs<3; ++hs){
            int h = gS*3 + hs;
            const float4* qp = (const float4*)(q + (size_t)i*192 + h*16);
            qv[hs][0]=qp[0]; qv[hs][1]=qp[1]; qv[hs][2]=qp[2]; qv[hs][3]=qp[3];
            const float4* gp4 = (const float4*)(gq + (size_t)i*144 + h*12);
            gqv[hs][0]=gp4[0]; gqv[hs][1]=gp4[1]; gqv[hs][2]=gp4[2];
            sqq3[hs] = sqq[(size_t)i*HD + h];
            float shv = scale_head[h];
            float sp = (shv > 20.f) ? shv : log1pf(__expf(shv));
            sp3[hs] = SCALE_FRAME * sp;
        }
    }

    STAGEA(0, 0);
    __syncthreads();   // wbT published; STAGEA(0) drained (syncthreads waits vmcnt 0)

    // pair waves: preload this lane's Wb half (16 f4) into registers
    float4 wbr[16];
    if (wave < 6){
        const float4* wb4 = (const float4*)wbT;
        #pragma unroll
        for (int m=0; m<16; ++m) wbr[m] = wb4[hpair*(WBS/4) + fh*16 + m];
    }

    float SFp0=0.f, SFp1=0.f, SFp2=0.f;

    // ---------------- phase A ----------------
    for (int jt=0; jt<24; ++jt){
        if (jt+1 < 24) STAGEA(jt+1, (jt+1)&1);
        if (wave < 6){
            const char* zb = (const char*)zbase + (size_t)(jt&1)*16384;
            int r0 = rlow, r1 = rlow + 16;
            const char* zr0 = zb + r0*512;
            const char* zr1 = zb + r1*512;
            int s0 = r0 << 4, s1 = r1 << 4;
            float acc0 = 0.f, acc1 = 0.f;
            #pragma unroll
            for (int cc=0; cc<16; ++cc){
                int c4 = fh*16 + cc;
                float4 z0 = *(const float4*)(zr0 + ((c4*16) ^ s0));
                float4 z1 = *(const float4*)(zr1 + ((c4*16) ^ s1));
                acc0 += dot4f(z0, wbr[cc]);
                acc1 += dot4f(z1, wbr[cc]);
            }
            float o0 = acc0 + __shfl_xor(acc0, 16);
            float o1 = acc1 + __shfl_xor(acc1, 16);
            if (fh == 0){
                a_l[hpair*ALS + jt*32 + r0] = o0;
                a_l[hpair*ALS + jt*32 + r1] = o1;
            }
        } else {
            // RMW previous tile (pair writes of jt-1 published by the end-of-iter barrier)
            if (jt > 0){
                int jp = (jt-1)*32 + rS;
                a_l[(gS*3+0)*ALS + jp] += SFp0;
                a_l[(gS*3+1)*ALS + jp] += SFp1;
                a_l[(gS*3+2)*ALS + jp] += SFp2;
            }
            int jg = jt*32 + rS;
            const float4* kp  = (const float4*)(k  + (size_t)jg*192);
            const float4* gkp = (const float4*)(gk + (size_t)jg*144);
            float sf[3];
            #pragma unroll
            for (int hs=0; hs<3; ++hs){
                int h = gS*3 + hs;
                float sng = dot4f(qv[hs][0], kp[h*4+0]) + dot4f(qv[hs][1], kp[h*4+1])
                          + dot4f(qv[hs][2], kp[h*4+2]) + dot4f(qv[hs][3], kp[h*4+3]);
                float fdot = dot4f(gqv[hs][0], gkp[h*3+0]) + dot4f(gqv[hs][1], gkp[h*3+1])
                           + dot4f(gqv[hs][2], gkp[h*3+2]);
                float d2 = sqq3[hs] + sqk[(size_t)jg*HD + h] - 2.0f*fdot;
                sf[hs] = fmaf(SCALE_SINGLE, sng, sp3[hs]*d2);
            }
            SFp0 = sf[0]; SFp1 = sf[1]; SFp2 = sf[2];
        }
        __syncthreads();   // publishes pair writes(jt), drains STAGE(jt+1)
    }
    if (wave >= 6){    // RMW last tile (published by final loop barrier)
        int jp = 23*32 + rS;
        a_l[(gS*3+0)*ALS + jp] += SFp0;
        a_l[(gS*3+1)*ALS + jp] += SFp1;
        a_l[(gS*3+2)*ALS + jp] += SFp2;
    }
    __syncthreads();

    // softmax: waves 0-5, 2 heads each
    if (wave < 6){
        #pragma unroll
        for (int hh=0; hh<2; ++hh){
            int h = wave*2 + hh;
            float4* row4 = (float4*)(a_l + h*ALS);
            float4 vls[3];
            #pragma unroll
            for (int qq=0; qq<3; ++qq) vls[qq] = row4[lane + 64*qq];
            float m = -1e30f;
            #pragma unroll
            for (int qq=0; qq<3; ++qq){
                m = fmaxf(m, fmaxf(fmaxf(vls[qq].x, vls[qq].y), fmaxf(vls[qq].z, vls[qq].w)));
            }
            #pragma unroll
            for (int off=32; off; off>>=1) m = fmaxf(m, __shfl_xor(m, off));
            float ssum = 0.f;
            #pragma unroll
            for (int qq=0; qq<3; ++qq){
                vls[qq].x = __expf(vls[qq].x - m); vls[qq].y = __expf(vls[qq].y - m);
                vls[qq].z = __expf(vls[qq].z - m); vls[qq].w = __expf(vls[qq].w - m);
                ssum += (vls[qq].x + vls[qq].y) + (vls[qq].z + vls[qq].w);
            }
            #pragma unroll
            for (int off=32; off; off>>=1) ssum += __shfl_xor(ssum, off);
            float inv = 1.0f/ssum;
            #pragma unroll
            for (int qq=0; qq<3; ++qq){
                vls[qq].x *= inv; vls[qq].y *= inv; vls[qq].z *= inv; vls[qq].w *= inv;
                row4[lane + 64*qq] = vls[qq];
            }
        }
    }
    __syncthreads();

    // ---------------- phase B ----------------
    STAGEB(0, 0);

    int c4 = lane & 31;
    int hoz = wave*2 + (lane>>5);          // waves 0-5: o_z head 0..11
    float4 az = {0,0,0,0};
    float4 accs = {0,0,0,0};
    const float4* gsrc = nullptr; int gstride = 0; int hso = 0;
    if (t >= 384 && t < 432){ int u=t-384; hso = u>>2; gsrc = (const float4*)v  + hso*4 + (u&3); gstride = 48; }
    else if (t >= 432 && t < 504){ int u=t-432; hso = u/6;  gsrc = (const float4*)gv + hso*6 + (u%6); gstride = 72; }

    __syncthreads();   // STAGEB(0) drained

    for (int jt=0; jt<24; ++jt){
        if (jt+1 < 24) STAGEB(jt+1, (jt+1)&1);
        if (wave < 6){
            const float4* zt4 = (const float4*)(zbase + (size_t)(jt&1)*4096);
            const float4* arow4 = (const float4*)(a_l + hoz*ALS) + jt*8;
            #pragma unroll
            for (int jq=0; jq<8; ++jq){
                float4 aa = arow4[jq];
                #pragma unroll
                for (int u=0; u<4; ++u){
                    float4 zv = zt4[(jq*4+u)*32 + c4];
                    float w = ((const float*)&aa)[u];
                    az.x = fmaf(w, zv.x, az.x);
                    az.y = fmaf(w, zv.y, az.y);
                    az.z = fmaf(w, zv.z, az.z);
                    az.w = fmaf(w, zv.w, az.w);
                }
            }
        } else if (t >= 384 && t < 504){
            const float* arow = a_l + hso*ALS;
            #pragma unroll
            for (int jj=0; jj<32; ++jj){
                int j = jt*32 + jj;
                float aw = arow[j];
                float4 sv = gsrc[(size_t)j*gstride];
                accs.x = fmaf(aw, sv.x, accs.x);
                accs.y = fmaf(aw, sv.y, accs.y);
                accs.z = fmaf(aw, sv.z, accs.z);
                accs.w = fmaf(aw, sv.w, accs.w);
            }
        }
        __syncthreads();
    }

    // epilogue
    if (wave < 6){
        *(float4*)(att + (size_t)i*DOUT + 192 + hoz*128 + c4*4) = az;
    } else if (t >= 384 && t < 432){
        int u = t-384;
        ((float4*)(att + (size_t)i*DOUT))[u] = accs;
    } else if (t >= 432 && t < 504){
        int u = t-432;
        ((float4*)so_l)[u] = accs;
    }
    __syncthreads();
    if (t < 96){
        int h = t >> 3, p = t & 7;
        float d0 = so_l[h*24+p*3+0] - tv[(size_t)i*3+0];
        float d1 = so_l[h*24+p*3+1] - tv[(size_t)i*3+1];
        float d2 = so_l[h*24+p*3+2] - tv[(size_t)i*3+2];
        const float* Ri = R + (size_t)i*9;
        float l0 = fmaf(Ri[0],d0, fmaf(Ri[3],d1, Ri[6]*d2));
        float l1 = fmaf(Ri[1],d0, fmaf(Ri[4],d1, Ri[7]*d2));
        float l2 = fmaf(Ri[2],d0, fmaf(Ri[5],d1, Ri[8]*d2));
        size_t base = (size_t)i*DOUT;
        att[base + 1728 + p*36 + h*3 + 0] = l0;
        att[base + 1728 + p*36 + h*3 + 1] = l1;
        att[base + 1728 + p*36 + h*3 + 2] = l2;
        att[base + 2016 + p*12 + h] = sqrtf(l0*l0 + l1*l1 + l2*l2);
    }
#undef STAGEA
#undef STAGEB
}

// ---------------- K4: final projection att @ Wout + bout ----------------
#define ROWS4 2
__global__ __launch_bounds__(384) void k_final(
    const float* __restrict__ att, const float* __restrict__ Wout, const float* __restrict__ bout,
    float* __restrict__ out)
{
    __shared__ float att_l[ROWS4*DOUT];
    int ib = blockIdx.x * ROWS4, t = threadIdx.x;
    for (int idx=t; idx<ROWS4*DOUT; idx+=384){
        att_l[idx] = att[(size_t)ib*DOUT + idx];
    }
    __syncthreads();
    float a0=0.f,a1=0.f,a2=0.f,a3=0.f;
    float b0=0.f,b1=0.f,b2=0.f,b3=0.f;
    #pragma unroll 4
    for (int d=0; d<DOUT; d+=4){
        float w0 = Wout[(size_t)(d+0)*CSD + t];
        float w1 = Wout[(size_t)(d+1)*CSD + t];
        float w2 = Wout[(size_t)(d+2)*CSD + t];
        float w3 = Wout[(size_t)(d+3)*CSD + t];
        a0 = fmaf(att_l[d+0], w0, a0);
        a1 = fmaf(att_l[d+1], w1, a1);
        a2 = fmaf(att_l[d+2], w2, a2);
        a3 = fmaf(att_l[d+3], w3, a3);
        b0 = fmaf(att_l[DOUT+d+0], w0, b0);
        b1 = fmaf(att_l[DOUT+d+1], w1, b1);
        b2 = fmaf(att_l[DOUT+d+2], w2, b2);
        b3 = fmaf(att_l[DOUT+d+3], w3, b3);
    }
    float bb = bout[t];
    out[(size_t)ib*CSD + t]     = bb + ((a0+a1)+(a2+a3));
    out[(size_t)(ib+1)*CSD + t] = bb + ((b0+b1)+(b2+b3));
}

extern "C" void kernel_launch(void* const* d_in, const int* in_sizes, int n_in,
                              void* d_out, int out_size, void* d_ws, size_t ws_size,
                              hipStream_t stream)
{
    const float* s   = (const float*)d_in[0];
    const float* z   = (const float*)d_in[1];
    const float* R   = (const float*)d_in[2];
    const float* tv  = (const float*)d_in[3];
    const float* Wq  = (const float*)d_in[4];
    const float* Wk  = (const float*)d_in[5];
    const float* Wv  = (const float*)d_in[6];
    const float* Wqp = (const float*)d_in[7];
    const float* Wkp = (const float*)d_in[8];
    const float* Wvp = (const float*)d_in[9];
    const float* Wb  = (const float*)d_in[10];
    const float* Wout= (const float*)d_in[11];
    const float* bout= (const float*)d_in[12];
    const float* sh  = (const float*)d_in[13];

    float* ws  = (float*)d_ws;
    float* q_  = ws;                 // 768*192
    float* k_  = q_  + 147456;       // 768*192
    float* v_  = k_  + 147456;       // 768*192
    float* gq_ = v_  + 147456;       // 768*144
    float* gk_ = gq_ + 110592;       // 768*144
    float* gv_ = gk_ + 110592;       // 768*288
    float* sqq_= gv_ + 221184;       // 768*12
    float* sqk_= sqq_ + 9216;        // 768*12
    float* att_= sqk_ + 9216;        // 768*2112
    float* out = (float*)d_out;

    hipLaunchKernelGGL(k_proj,  dim3(NN/II), dim3(384), 0, stream,
                       s,R,tv,Wq,Wk,Wv,Wqp,Wkp,Wvp, q_,k_,v_,gq_,gk_,gv_,sqq_,sqk_);
    hipLaunchKernelGGL(k_ipa,   dim3(NN),    dim3(512), 0, stream,
                       z,Wb,sh,q_,k_,gq_,gk_,sqq_,sqk_, v_,gv_,R,tv, att_);
    hipLaunchKernelGGL(k_final, dim3(NN/ROWS4), dim3(384), 0, stream,
                       att_,Wout,bout, out);
}

// Round 10
// 728.685 us; speedup vs baseline: 1.4486x; 1.4486x over previous
//
#include <hip/hip_runtime.h>
#include <hip/hip_bf16.h>

#define NN 768
#define CSD 384
#define CZD 128
#define HD 12
#define DOUT 2112
#define II 2

#define SCALE_SINGLE 0.25f
#define SCALE_FRAME (-0.11785113019775793f)   /* -1/sqrt(72) */

__device__ __forceinline__ float dot4f(float4 a, float4 b){
    return fmaf(a.x,b.x, fmaf(a.y,b.y, fmaf(a.z,b.z, a.w*b.w)));
}

// ---------------- K1: projections + frame apply, II=2 residues per block ----------------
__global__ __launch_bounds__(384) void k_proj(
    const float* __restrict__ s, const float* __restrict__ R, const float* __restrict__ tv,
    const float* __restrict__ Wq, const float* __restrict__ Wk, const float* __restrict__ Wv,
    const float* __restrict__ Wqp, const float* __restrict__ Wkp, const float* __restrict__ Wvp,
    float* __restrict__ q, float* __restrict__ k, float* __restrict__ v,
    float* __restrict__ gq, float* __restrict__ gk, float* __restrict__ gv,
    float* __restrict__ sqq, float* __restrict__ sqk)
{
    __shared__ float s_l[II*CSD];
    __shared__ float praw[II][576];
    __shared__ float sq_pt[II][96];
    int i0 = blockIdx.x * II, t = threadIdx.x;
    if (t < II*CSD/4){
        const float4* s4 = (const float4*)(s + (size_t)i0*CSD);
        ((float4*)s_l)[t] = s4[t];
    }
    __syncthreads();

    int cols[3] = {t, t+384, t+768};
    const float* Wp[3]; int st[3], lc[3];
    #pragma unroll
    for (int m=0;m<3;m++){
        int c = cols[m];
        if (c < 192){ Wp[m]=Wq;  st[m]=192; lc[m]=c; }
        else if (c < 384){ Wp[m]=Wk;  st[m]=192; lc[m]=c-192; }
        else if (c < 576){ Wp[m]=Wv;  st[m]=192; lc[m]=c-384; }
        else if (c < 720){ Wp[m]=Wqp; st[m]=144; lc[m]=c-576; }
        else if (c < 864){ Wp[m]=Wkp; st[m]=144; lc[m]=c-720; }
        else { Wp[m]=Wvp; st[m]=288; lc[m]=c-864; }
    }
    float acc[3][II];
    #pragma unroll
    for (int m=0;m<3;m++)
        #pragma unroll
        for (int ii=0;ii<II;ii++) acc[m][ii]=0.f;

    #pragma unroll 4
    for (int r=0;r<CSD;r++){
        float w0 = Wp[0][(size_t)r*st[0]+lc[0]];
        float w1 = Wp[1][(size_t)r*st[1]+lc[1]];
        float w2 = Wp[2][(size_t)r*st[2]+lc[2]];
        #pragma unroll
        for (int ii=0;ii<II;ii++){
            float sv = s_l[ii*CSD + r];
            acc[0][ii] = fmaf(sv, w0, acc[0][ii]);
            acc[1][ii] = fmaf(sv, w1, acc[1][ii]);
            acc[2][ii] = fmaf(sv, w2, acc[2][ii]);
        }
    }
    #pragma unroll
    for (int m=0;m<3;m++){
        int c = cols[m];
        #pragma unroll
        for (int ii=0;ii<II;ii++){
            float val = acc[m][ii];
            size_t i = i0 + ii;
            if (c < 192) q[i*192 + c] = val;
            else if (c < 384) k[i*192 + (c-192)] = val;
            else if (c < 576) v[i*192 + (c-384)] = val;
            else praw[ii][c-576] = val;
        }
    }
    __syncthreads();

    if (t < 192){
        #pragma unroll
        for (int ii=0;ii<II;ii++){
            size_t i = i0 + ii;
            const float* Ri = R + i*9;
            float R00=Ri[0],R01=Ri[1],R02=Ri[2];
            float R10=Ri[3],R11=Ri[4],R12=Ri[5];
            float R20=Ri[6],R21=Ri[7],R22=Ri[8];
            float t0=tv[i*3+0],t1=tv[i*3+1],t2=tv[i*3+2];
            int src; float* dst; int sqslot=-1;
            if (t < 48){ src = t*3; dst = gq + i*144 + t*3; sqslot = t; }
            else if (t < 96){ int u=t-48; src = 144+u*3; dst = gk + i*144 + u*3; sqslot = 48+u; }
            else { int u=t-96; src = 288+u*3; dst = gv + i*288 + u*3; }
            float x=praw[ii][src], y=praw[ii][src+1], zc=praw[ii][src+2];
            float g0 = fmaf(R00,x, fmaf(R01,y, fmaf(R02,zc, t0)));
            float g1 = fmaf(R10,x, fmaf(R11,y, fmaf(R12,zc, t1)));
            float g2 = fmaf(R20,x, fmaf(R21,y, fmaf(R22,zc, t2)));
            dst[0]=g0; dst[1]=g1; dst[2]=g2;
            if (sqslot >= 0) sq_pt[ii][sqslot] = g0*g0 + g1*g1 + g2*g2;
        }
    }
    __syncthreads();
    if (t < II*HD){
        int ii = t / HD, h = t % HD;
        float s1 = sq_pt[ii][h*4]+sq_pt[ii][h*4+1]+sq_pt[ii][h*4+2]+sq_pt[ii][h*4+3];
        float s2 = sq_pt[ii][48+h*4]+sq_pt[ii][48+h*4+1]+sq_pt[ii][48+h*4+2]+sq_pt[ii][48+h*4+3];
        sqq[(size_t)(i0+ii)*HD + h] = s1;
        sqk[(size_t)(i0+ii)*HD + h] = s2;
    }
}

// ---------------- K2: fused IPA, SINGLE z pass with online softmax ----------------
// 512 threads = 8 waves, ~45KB LDS. z[i] streamed once (24 tiles x 32 rows, dbuf).
// Per tile: [bar1] stage(jt+1); waves 0-5 (lane=(j,h)): pair-dot from LDS + SF from
// LDS (computed one tile ahead by waves 6-7) -> online softmax update (shfl within
// 32-lane half) -> w,scale to LDS; waves 6-7: SF(jt+1). [bar2] waves 0-5: o_z
// accumulate (rescale+w*z from same tile); waves 6-7: o_s/so accumulate from L2.
__global__ __launch_bounds__(512) void k_ipa(
    const float* __restrict__ z, const float* __restrict__ Wb, const float* __restrict__ scale_head,
    const float* __restrict__ q, const float* __restrict__ k,
    const float* __restrict__ gq, const float* __restrict__ gk,
    const float* __restrict__ sqq, const float* __restrict__ sqk,
    const float* __restrict__ v, const float* __restrict__ gv,
    const float* __restrict__ R, const float* __restrict__ tv,
    float* __restrict__ att)
{
    __shared__ float ztile[2][32][CZD];   // 32KB dbuf
    __shared__ float wbT[HD*CZD];         // [h][c], broadcast-read
    __shared__ float SFl[2][HD][32];      // single+frame terms, 1 tile ahead
    __shared__ float w_l[HD][32];         // this tile's softmax numerators
    __shared__ float scale_l[HD];         // this tile's rescale factor
    __shared__ float s_l[HD];             // final denominators
    __shared__ float so_l[288];

    int i = blockIdx.x, t = threadIdx.x;
    int wave = t >> 6, lane = t & 63;

    for (int idx=t; idx<HD*CZD; idx+=512){
        int h = idx >> 7, c = idx & 127;
        wbT[idx] = Wb[(size_t)c*HD + h];
    }

    const char* zi = (const char*)(z + (size_t)i*NN*CZD);
    float* zbase = &ztile[0][0][0];

    // 16KB tile, 512 threads x 2 x 16B; linear LDS dest, inverse-swizzled global src
#define STAGE(JT, BUF) do { \
    const char* _zb = zi + (size_t)(JT)*16384; \
    char* _lb = (char*)zbase + (size_t)(BUF)*16384; \
    _Pragma("unroll") \
    for (int _m=0;_m<2;_m++){ \
        int _d = t*16 + _m*8192; \
        int _j = _d >> 9; \
        int _b = _d & 511; \
        int _sb = _b ^ ((_j & 31) << 4); \
        __builtin_amdgcn_global_load_lds((const __attribute__((address_space(1))) void*)(_zb + (size_t)_j*512 + _sb), \
            (__attribute__((address_space(3))) void*)(_lb + _d), 16, 0, 0); \
    } \
  } while(0)

    // roles
    int jl = lane & 31, hh = lane >> 5;
    int h = wave*2 + hh;                               // waves 0-5: logit/o_z head
    int rS = lane & 31, gS = (wave-6)*2 + (lane>>5);   // waves 6-7: SF head-triple

    float4 qv[3][4]; float4 gqv[3][3]; float sqq3[3], sp3[3];
    const float4* gsrc = nullptr; int gstride = 0; int hso = 0;
    if (wave >= 6){
        #pragma unroll
        for (int hs=0; hs<3; ++hs){
            int hq = gS*3 + hs;
            const float4* qp = (const float4*)(q + (size_t)i*192 + hq*16);
            qv[hs][0]=qp[0]; qv[hs][1]=qp[1]; qv[hs][2]=qp[2]; qv[hs][3]=qp[3];
            const float4* gp4 = (const float4*)(gq + (size_t)i*144 + hq*12);
            gqv[hs][0]=gp4[0]; gqv[hs][1]=gp4[1]; gqv[hs][2]=gp4[2];
            sqq3[hs] = sqq[(size_t)i*HD + hq];
            float shv = scale_head[hq];
            float sp = (shv > 20.f) ? shv : log1pf(__expf(shv));
            sp3[hs] = SCALE_FRAME * sp;
        }
        if (t >= 384 && t < 432){ int u=t-384; hso = u>>2; gsrc = (const float4*)v  + hso*4 + (u&3); gstride = 48; }
        else if (t >= 432 && t < 504){ int u=t-432; hso = u/6;  gsrc = (const float4*)gv + hso*6 + (u%6); gstride = 72; }
    }

    STAGE(0, 0);
    __syncthreads();   // wbT visible; STAGE(0) drained

    // prologue: SF(0)
    if (wave >= 6){
        int jg = rS;
        const float4* kp  = (const float4*)(k  + (size_t)jg*192);
        const float4* gkp = (const float4*)(gk + (size_t)jg*144);
        #pragma unroll
        for (int hs=0; hs<3; ++hs){
            int hq = gS*3 + hs;
            float sng = dot4f(qv[hs][0], kp[hq*4+0]) + dot4f(qv[hs][1], kp[hq*4+1])
                      + dot4f(qv[hs][2], kp[hq*4+2]) + dot4f(qv[hs][3], kp[hq*4+3]);
            float fdot = dot4f(gqv[hs][0], gkp[hq*3+0]) + dot4f(gqv[hs][1], gkp[hq*3+1])
                       + dot4f(gqv[hs][2], gkp[hq*3+2]);
            float d2 = sqq3[hs] + sqk[(size_t)jg*HD + hq] - 2.0f*fdot;
            SFl[0][hq][rS] = fmaf(SCALE_SINGLE, sng, sp3[hs]*d2);
        }
    }

    float m_run = -1e30f, s_run = 0.f;
    float4 az = {0,0,0,0};     // o_z accumulator (waves 0-5)
    float4 accs = {0,0,0,0};   // o_s/so accumulator (waves 6-7)

    for (int jt=0; jt<24; ++jt){
        __syncthreads();   // bar1: ztile[jt] + SFl[jt] + (w_l consumed) ready
        if (jt+1 < 24) STAGE(jt+1, (jt+1)&1);

        if (wave < 6){
            // pair logit for (j=jl, h)
            const char* zb = (const char*)zbase + (size_t)(jt&1)*16384 + (size_t)jl*512;
            int xo = jl << 4;
            const float4* wb4 = (const float4*)(wbT + h*CZD);
            float acc = 0.f;
            #pragma unroll
            for (int c4=0; c4<32; ++c4){
                float4 zv = *(const float4*)(zb + ((c4*16) ^ xo));
                acc += dot4f(zv, wb4[c4]);
            }
            float L = acc + SFl[jt&1][h][jl];
            // online softmax update within 32-lane half (one head)
            float tmax = L;
            #pragma unroll
            for (int off=16; off; off>>=1) tmax = fmaxf(tmax, __shfl_xor(tmax, off));
            float mnew = fmaxf(m_run, tmax);
            float sc = __expf(m_run - mnew);
            float w = __expf(L - mnew);
            float tsum = w;
            #pragma unroll
            for (int off=16; off; off>>=1) tsum += __shfl_xor(tsum, off);
            s_run = fmaf(s_run, sc, tsum);
            m_run = mnew;
            w_l[h][jl] = w;
            if (jl == 0) scale_l[h] = sc;
        } else if (jt+1 < 24){
            // SF for next tile
            int jg = (jt+1)*32 + rS;
            const float4* kp  = (const float4*)(k  + (size_t)jg*192);
            const float4* gkp = (const float4*)(gk + (size_t)jg*144);
            #pragma unroll
            for (int hs=0; hs<3; ++hs){
                int hq = gS*3 + hs;
                float sng = dot4f(qv[hs][0], kp[hq*4+0]) + dot4f(qv[hs][1], kp[hq*4+1])
                          + dot4f(qv[hs][2], kp[hq*4+2]) + dot4f(qv[hs][3], kp[hq*4+3]);
                float fdot = dot4f(gqv[hs][0], gkp[hq*3+0]) + dot4f(gqv[hs][1], gkp[hq*3+1])
                           + dot4f(gqv[hs][2], gkp[hq*3+2]);
                float d2 = sqq3[hs] + sqk[(size_t)jg*HD + hq] - 2.0f*fdot;
                SFl[(jt+1)&1][hq][rS] = fmaf(SCALE_SINGLE, sng, sp3[hs]*d2);
            }
        }
        __syncthreads();   // bar2: w_l + scale_l published; STAGE(jt+1) drained

        if (wave < 6){
            // o_z accumulate: az = az*sc + sum_j w[j]*z[j][c4]  (c4 == jl)
            float scl = scale_l[h];
            float4 wreg[8];
            const float4* wrow = (const float4*)&w_l[h][0];
            #pragma unroll
            for (int mq=0; mq<8; ++mq) wreg[mq] = wrow[mq];
            az.x *= scl; az.y *= scl; az.z *= scl; az.w *= scl;
            const char* zb2 = (const char*)zbase + (size_t)(jt&1)*16384;
            int xo2 = jl << 4;
            #pragma unroll
            for (int j=0; j<32; ++j){
                float w = ((const float*)wreg)[j];
                float4 zv = *(const float4*)(zb2 + (size_t)j*512 + ((xo2) ^ (j<<4)));
                az.x = fmaf(w, zv.x, az.x);
                az.y = fmaf(w, zv.y, az.y);
                az.z = fmaf(w, zv.z, az.z);
                az.w = fmaf(w, zv.w, az.w);
            }
        } else if (t >= 384 && t < 504){
            float scl = scale_l[hso];
            accs.x *= scl; accs.y *= scl; accs.z *= scl; accs.w *= scl;
            const float* wrow = &w_l[hso][0];
            #pragma unroll
            for (int j=0; j<32; ++j){
                float w = wrow[j];
                float4 sv = gsrc[(size_t)(jt*32 + j)*gstride];
                accs.x = fmaf(w, sv.x, accs.x);
                accs.y = fmaf(w, sv.y, accs.y);
                accs.z = fmaf(w, sv.z, accs.z);
                accs.w = fmaf(w, sv.w, accs.w);
            }
        }
    }

    if (wave < 6 && jl == 0) s_l[h] = s_run;
    __syncthreads();

    // epilogue: normalize + write
    if (wave < 6){
        float inv = 1.0f / s_l[h];
        az.x *= inv; az.y *= inv; az.z *= inv; az.w *= inv;
        *(float4*)(att + (size_t)i*DOUT + 192 + h*128 + jl*4) = az;
    } else if (t >= 384 && t < 432){
        float inv = 1.0f / s_l[hso];
        accs.x *= inv; accs.y *= inv; accs.z *= inv; accs.w *= inv;
        int u = t-384;
        ((float4*)(att + (size_t)i*DOUT))[u] = accs;
    } else if (t >= 432 && t < 504){
        float inv = 1.0f / s_l[hso];
        accs.x *= inv; accs.y *= inv; accs.z *= inv; accs.w *= inv;
        int u = t-432;
        ((float4*)so_l)[u] = accs;
    }
    __syncthreads();
    if (t < 96){
        int hq = t >> 3, p = t & 7;
        float d0 = so_l[hq*24+p*3+0] - tv[(size_t)i*3+0];
        float d1 = so_l[hq*24+p*3+1] - tv[(size_t)i*3+1];
        float d2 = so_l[hq*24+p*3+2] - tv[(size_t)i*3+2];
        const float* Ri = R + (size_t)i*9;
        float l0 = fmaf(Ri[0],d0, fmaf(Ri[3],d1, Ri[6]*d2));
        float l1 = fmaf(Ri[1],d0, fmaf(Ri[4],d1, Ri[7]*d2));
        float l2 = fmaf(Ri[2],d0, fmaf(Ri[5],d1, Ri[8]*d2));
        size_t base = (size_t)i*DOUT;
        att[base + 1728 + p*36 + hq*3 + 0] = l0;
        att[base + 1728 + p*36 + hq*3 + 1] = l1;
        att[base + 1728 + p*36 + hq*3 + 2] = l2;
        att[base + 2016 + p*12 + hq] = sqrtf(l0*l0 + l1*l1 + l2*l2);
    }
#undef STAGE
}

// ---------------- K4: final projection att @ Wout + bout ----------------
#define ROWS4 2
__global__ __launch_bounds__(384) void k_final(
    const float* __restrict__ att, const float* __restrict__ Wout, const float* __restrict__ bout,
    float* __restrict__ out)
{
    __shared__ float att_l[ROWS4*DOUT];
    int ib = blockIdx.x * ROWS4, t = threadIdx.x;
    for (int idx=t; idx<ROWS4*DOUT; idx+=384){
        att_l[idx] = att[(size_t)ib*DOUT + idx];
    }
    __syncthreads();
    float a0=0.f,a1=0.f,a2=0.f,a3=0.f;
    float b0=0.f,b1=0.f,b2=0.f,b3=0.f;
    #pragma unroll 4
    for (int d=0; d<DOUT; d+=4){
        float w0 = Wout[(size_t)(d+0)*CSD + t];
        float w1 = Wout[(size_t)(d+1)*CSD + t];
        float w2 = Wout[(size_t)(d+2)*CSD + t];
        float w3 = Wout[(size_t)(d+3)*CSD + t];
        a0 = fmaf(att_l[d+0], w0, a0);
        a1 = fmaf(att_l[d+1], w1, a1);
        a2 = fmaf(att_l[d+2], w2, a2);
        a3 = fmaf(att_l[d+3], w3, a3);
        b0 = fmaf(att_l[DOUT+d+0], w0, b0);
        b1 = fmaf(att_l[DOUT+d+1], w1, b1);
        b2 = fmaf(att_l[DOUT+d+2], w2, b2);
        b3 = fmaf(att_l[DOUT+d+3], w3, b3);
    }
    float bb = bout[t];
    out[(size_t)ib*CSD + t]     = bb + ((a0+a1)+(a2+a3));
    out[(size_t)(ib+1)*CSD + t] = bb + ((b0+b1)+(b2+b3));
}

extern "C" void kernel_launch(void* const* d_in, const int* in_sizes, int n_in,
                              void* d_out, int out_size, void* d_ws, size_t ws_size,
                              hipStream_t stream)
{
    const float* s   = (const float*)d_in[0];
    const float* z   = (const float*)d_in[1];
    const float* R   = (const float*)d_in[2];
    const float* tv  = (const float*)d_in[3];
    const float* Wq  = (const float*)d_in[4];
    const float* Wk  = (const float*)d_in[5];
    const float* Wv  = (const float*)d_in[6];
    const float* Wqp = (const float*)d_in[7];
    const float* Wkp = (const float*)d_in[8];
    const float* Wvp = (const float*)d_in[9];
    const float* Wb  = (const float*)d_in[10];
    const float* Wout= (const float*)d_in[11];
    const float* bout= (const float*)d_in[12];
    const float* sh  = (const float*)d_in[13];

    float* ws  = (float*)d_ws;
    float* q_  = ws;                 // 768*192
    float* k_  = q_  + 147456;       // 768*192
    float* v_  = k_  + 147456;       // 768*192
    float* gq_ = v_  + 147456;       // 768*144
    float* gk_ = gq_ + 110592;       // 768*144
    float* gv_ = gk_ + 110592;       // 768*288
    float* sqq_= gv_ + 221184;       // 768*12
    float* sqk_= sqq_ + 9216;        // 768*12
    float* att_= sqk_ + 9216;        // 768*2112
    float* out = (float*)d_out;

    hipLaunchKernelGGL(k_proj,  dim3(NN/II), dim3(384), 0, stream,
                       s,R,tv,Wq,Wk,Wv,Wqp,Wkp,Wvp, q_,k_,v_,gq_,gk_,gv_,sqq_,sqk_);
    hipLaunchKernelGGL(k_ipa,   dim3(NN),    dim3(512), 0, stream,
                       z,Wb,sh,q_,k_,gq_,gk_,sqq_,sqk_, v_,gv_,R,tv, att_);
    hipLaunchKernelGGL(k_final, dim3(NN/ROWS4), dim3(384), 0, stream,
                       att_,Wout,bout, out);
}